// Round 2
// baseline (255.635 us; speedup 1.0000x reference)
//
#include <hip/hip_runtime.h>

#define NODES 50000
#define FEAT 128
#define EDGES 800000
#define GRAPHS 512
#define NB 196      // dst buckets (dst >> 8), 196*256 = 50176 >= NODES
#define CHUNK 4096
#define ABLK 196    // ceil(EDGES/CHUNK)
#define BCAP 8192   // max edges per bucket (mean 4082, max ~4400)
#define PROJ_BLOCKS 782

typedef unsigned int u32;
typedef unsigned short u16;
typedef __attribute__((ext_vector_type(8))) short short8;   // 8 bf16 = 4 VGPRs
typedef __attribute__((ext_vector_type(4))) float v4f;      // MFMA accumulator
typedef __attribute__((ext_vector_type(4))) u32 u32x4;
typedef __attribute__((ext_vector_type(2))) float f2;       // packed-fp32 pair

static __device__ __forceinline__ float bflo(u32 u){ return __uint_as_float(u << 16); }
static __device__ __forceinline__ float bfhi(u32 u){ return __uint_as_float(u & 0xffff0000u); }
static __device__ __forceinline__ u16 f2bf(float f){
  u32 u = __float_as_uint(f);
  u32 r = u + 0x7fffu + ((u >> 16) & 1u);
  return (u16)(r >> 16);
}
static __device__ __forceinline__ u32 packbf(float a, float b){
  return (u32)f2bf(a) | ((u32)f2bf(b) << 16);
}
static __device__ __forceinline__ f2 unpk(u32 u){ f2 r; r.x = bflo(u); r.y = bfhi(u); return r; }
static __device__ __forceinline__ f2 vmax2(f2 a, f2 b){ f2 r; r.x = fmaxf(a.x,b.x); r.y = fmaxf(a.y,b.y); return r; }

// ---------------- fused: MFMA projection (blocks 0..781) + bucket hist -------
// srcp/dstp are now HEAD-MAJOR: [H][NODES][16] bf16, so that the aggregate
// kernel's per-head gather footprint is 1.6 MB (fits a 4 MiB per-XCD L2).
#define LROW 68
__global__ __launch_bounds__(256) void proj_hist_kernel(
    const float* __restrict__ x, const float* __restrict__ Wsrc,
    const float* __restrict__ Wdst, u16* __restrict__ srcp, u16* __restrict__ dstp,
    const int* __restrict__ ei, int* __restrict__ bcount)
{
  __shared__ u32 x_lds[64 * LROW];
  __shared__ int cnt[NB];
  const int t = threadIdx.x;

  if (blockIdx.x >= PROJ_BLOCKS){
    // ---- histogram role ----
    const int b = blockIdx.x - PROJ_BLOCKS;
    for (int k = t; k < NB; k += 256) cnt[k] = 0;
    __syncthreads();
    const int e0 = b * CHUNK;
    const int e1 = (e0 + CHUNK < EDGES) ? e0 + CHUNK : EDGES;
    for (int e = e0 + t; e < e1; e += 256)
      atomicAdd(&cnt[ei[EDGES + e] >> 8], 1);
    __syncthreads();
    // transposed layout: bcount[chunk][bucket] -> coalesced write over k
    for (int k = t; k < NB; k += 256) bcount[b * NB + k] = cnt[k];
    return;
  }

  // ---- projection role ----
  const int node0 = blockIdx.x * 64;
  const int rows_valid = NODES - node0 < 64 ? NODES - node0 : 64;
  const float4* xp = (const float4*)(x + (size_t)node0 * 128);
  for (int idx = t; idx < rows_valid * 32; idx += 256){
    const float4 v = xp[idx];
    const int row = idx >> 5, cq = idx & 31;
    x_lds[row * LROW + cq * 2]     = packbf(v.x, v.y);
    x_lds[row * LROW + cq * 2 + 1] = packbf(v.z, v.w);
  }

  const int wave = t >> 6, lane = t & 63;
  const int r16 = lane & 15;
  const int quad = lane >> 4;
  const int ko = quad * 4;
  const int n0 = wave * 32;

  short8 bs[2][4], bd[2][4];
  #pragma unroll
  for (int nt = 0; nt < 2; ++nt){
    const int col = n0 + nt * 16 + r16;
    #pragma unroll
    for (int k = 0; k < 4; ++k){
      const float4* wp = (const float4*)(Wsrc + col * 128 + quad * 8 + k * 32);
      float4 w0 = wp[0], w1 = wp[1];
      u32x4 pk; pk.x = packbf(w0.x,w0.y); pk.y = packbf(w0.z,w0.w);
      pk.z = packbf(w1.x,w1.y); pk.w = packbf(w1.z,w1.w);
      bs[nt][k] = __builtin_bit_cast(short8, pk);
      const float4* vp = (const float4*)(Wdst + col * 128 + quad * 8 + k * 32);
      float4 v0 = vp[0], v1 = vp[1];
      u32x4 qk; qk.x = packbf(v0.x,v0.y); qk.y = packbf(v0.z,v0.w);
      qk.z = packbf(v1.x,v1.y); qk.w = packbf(v1.z,v1.w);
      bd[nt][k] = __builtin_bit_cast(short8, qk);
    }
  }
  __syncthreads();

  #pragma unroll
  for (int mt = 0; mt < 4; ++mt){
    const int node_base = node0 + mt * 16;
    if (node_base >= NODES) break;
    short8 afr[4];
    #pragma unroll
    for (int k = 0; k < 4; ++k)
      afr[k] = *(const short8*)&x_lds[(mt * 16 + r16) * LROW + ko + k * 16];
    v4f s0 = {0.f,0.f,0.f,0.f}, s1 = s0, d0 = s0, d1 = s0;
    #pragma unroll
    for (int k = 0; k < 4; ++k){
      s0 = __builtin_amdgcn_mfma_f32_16x16x32_bf16(afr[k], bs[0][k], s0, 0, 0, 0);
      s1 = __builtin_amdgcn_mfma_f32_16x16x32_bf16(afr[k], bs[1][k], s1, 0, 0, 0);
      d0 = __builtin_amdgcn_mfma_f32_16x16x32_bf16(afr[k], bd[0][k], d0, 0, 0, 0);
      d1 = __builtin_amdgcn_mfma_f32_16x16x32_bf16(afr[k], bd[1][k], d1, 0, 0, 0);
    }
    // C/D layout: col = lane&15, row = quad*4 + reg  [verified m89/m91]
    // cols [n0, n0+16) -> head wave*2 ; cols [n0+16, n0+32) -> head wave*2+1
    const int node = node_base + quad * 4;
    u16* so0 = srcp + ((size_t)(wave*2)   * NODES + node) * 16 + r16;
    u16* so1 = srcp + ((size_t)(wave*2+1) * NODES + node) * 16 + r16;
    u16* dd0 = dstp + ((size_t)(wave*2)   * NODES + node) * 16 + r16;
    u16* dd1 = dstp + ((size_t)(wave*2+1) * NODES + node) * 16 + r16;
    #pragma unroll
    for (int r = 0; r < 4; ++r){
      so0[r * 16] = f2bf(s0[r]);
      so1[r * 16] = f2bf(s1[r]);
      dd0[r * 16] = f2bf(d0[r]);
      dd1[r * 16] = f2bf(d1[r]);
    }
  }
}

// ---------------- scatter with inline scan -----------------------------------
// Also zeroes the per-node gate-logit accumulator (wsum) for aggregate.
__global__ __launch_bounds__(256) void bucket_scatter_kernel(
    const int* __restrict__ ei, const int* __restrict__ bcount,
    int* __restrict__ bstart_g, u32* __restrict__ ebuf, float* __restrict__ wsum)
{
  __shared__ int tot[256];
  __shared__ int bstart_s[NB + 1];
  __shared__ int obase_s[NB];
  __shared__ int cur[NB];
  const int b = blockIdx.x, t = threadIdx.x;
  const int nid = b * 256 + t;
  if (nid < NODES) wsum[nid] = 0.f;
  int total = 0, obase = 0;
  if (t < NB){
    int run = 0;
    for (int q = 0; q < ABLK; ++q){
      if (q == b) obase = run;
      run += bcount[q * NB + t];   // coalesced: consecutive t -> consecutive addr
    }
    total = run;
  }
  tot[t] = total;
  __syncthreads();
  const int v = total;
  for (int off = 1; off < 256; off <<= 1){
    const int add = (t >= off) ? tot[t - off] : 0;
    __syncthreads();
    tot[t] += add;
    __syncthreads();
  }
  if (t < NB){
    bstart_s[t] = tot[t] - v;
    obase_s[t] = obase;
    cur[t] = 0;
  }
  if (t == NB - 1) bstart_s[NB] = tot[t];
  __syncthreads();
  if (b == 0 && t <= NB) bstart_g[t] = bstart_s[t];

  const int e0 = b * CHUNK;
  const int e1 = (e0 + CHUNK < EDGES) ? e0 + CHUNK : EDGES;
  for (int e = e0 + t; e < e1; e += 256){
    const int d = ei[EDGES + e];
    const int s = ei[e];
    const int k = d >> 8;
    const int r = atomicAdd(&cur[k], 1);
    ebuf[bstart_s[k] + obase_s[k] + r] = (u32)s | ((u32)(d & 255) << 16);
  }
}

// ---------------- B4: one block per bucket: local CSR in LDS -----------------
// srclist is u16 now (src ids < 65536) -> halves srclist traffic; it is
// re-read once per head by aggregate.
__global__ __launch_bounds__(256) void bucket_csr_kernel(
    const u32* __restrict__ ebuf, const int* __restrict__ bstart,
    int* __restrict__ row_start, u16* __restrict__ srclist)
{
  __shared__ int cnt[256], excl[256], cur[256];
  __shared__ u32 loc[BCAP];
  const int k = blockIdx.x, t = threadIdx.x;
  const int base = bstart[k];
  int ne = bstart[k + 1] - base;
  if (ne > BCAP) ne = BCAP;
  cnt[t] = 0;
  __syncthreads();
  for (int j = t; j < ne; j += 256)
    atomicAdd(&cnt[(ebuf[base + j] >> 16) & 255], 1);
  __syncthreads();
  const int v = cnt[t];
  for (int off = 1; off < 256; off <<= 1){
    const int add = (t >= off) ? cnt[t - off] : 0;
    __syncthreads();
    cnt[t] += add;
    __syncthreads();
  }
  excl[t] = cnt[t] - v;
  cur[t] = cnt[t] - v;
  __syncthreads();
  const int node = k * 256 + t;
  if (node <= NODES) row_start[node] = base + excl[t];
  for (int j = t; j < ne; j += 256){
    const u32 e = ebuf[base + j];
    const int p = atomicAdd(&cur[(e >> 16) & 255], 1);
    loc[p] = e & 0xFFFFu;
  }
  __syncthreads();
  for (int j = t; j < ne; j += 256)
    srclist[base + j] = (u16)loc[j];
}

// ---------------- fused attention aggregation (head-sliced, XCD-pinned) -----
// head = blockIdx.x & 7: with round-robin block->XCD dispatch each XCD only
// gathers from its own 1.6 MB srcp head slice -> L2-resident (was 45 MB of
// L2 capacity misses). Wave = 2 nodes x 16 edge-slots x 2 dim-halves.
// Epilogue uses reduce-scatter: each lane ends owning ONE output dim.
__global__ __launch_bounds__(256) void aggregate_kernel(
    const u16* __restrict__ srcp, const u16* __restrict__ dstp,
    const int* __restrict__ row_start, const u16* __restrict__ srclist,
    const float* __restrict__ x, const float* __restrict__ attn,
    const float* __restrict__ bias, const float* __restrict__ palpha,
    const float* __restrict__ ww, float* __restrict__ outp,
    float* __restrict__ wsum)
{
  const int h   = blockIdx.x & 7;     // head, pinned to XCD (round-robin)
  const int grp = blockIdx.x >> 3;    // node group (8 nodes per block)
  const int wv = threadIdx.x >> 6;
  const int lane = threadIdx.x & 63;
  const int half = lane >> 5;         // node within wave
  const int l32 = lane & 31;
  const int es = l32 >> 1;            // edge slot 0..15
  const int dh = lane & 1;            // dim half: dims dh*8 .. dh*8+7
  const int i = grp * 8 + wv * 2 + half;
  const size_t hN = (size_t)h * NODES;
  const uint4* sp = (const uint4*)srcp;

  // dst fragment + attention vector (8 dims for this lane)
  f2 d2[4], a2[4];
  {
    const uint4 dv = ((const uint4*)dstp)[(hN + i) * 2 + dh];
    d2[0]=unpk(dv.x); d2[1]=unpk(dv.y); d2[2]=unpk(dv.z); d2[3]=unpk(dv.w);
    const float4* ap = (const float4*)(attn + h * 16 + dh * 8);
    const float4 a0 = ap[0], a1 = ap[1];
    a2[0].x=a0.x; a2[0].y=a0.y; a2[1].x=a0.z; a2[1].y=a0.w;
    a2[2].x=a1.x; a2[2].y=a1.y; a2[3].x=a1.z; a2[3].y=a1.w;
  }
  const int lo = row_start[i], hi = row_start[i + 1];
  const int deg = hi - lo;
  int myidx = 0;
  if (l32 < deg) myidx = (int)srclist[lo + l32];
  const int nb = (deg + 15) >> 4;
  int nbw = nb; { const int o = __shfl_xor(nb, 32); if (o > nbw) nbw = o; }

  f2 acc[4];
  #pragma unroll
  for (int q = 0; q < 4; ++q){ acc[q].x = 0.f; acc[q].y = 0.f; }
  float denom = 0.f;

  auto COMP = [&](bool valid, const uint4& A){
    f2 sv[4];
    sv[0]=unpk(A.x); sv[1]=unpk(A.y); sv[2]=unpk(A.z); sv[3]=unpk(A.w);
    f2 p; p.x = 0.f; p.y = 0.f;
    #pragma unroll
    for (int q = 0; q < 4; ++q){
      f2 e = sv[q] + d2[q];
      e = vmax2(e, e * 0.2f);
      p += e * a2[q];
    }
    const float p8 = p.x + p.y;
    const float lg = p8 + __shfl_xor(p8, 1);   // pair over dh -> full 16-dim dot
    const float w = valid ? __expf(lg) : 0.f;
    denom += w;
    f2 w2; w2.x = w; w2.y = w;
    #pragma unroll
    for (int q = 0; q < 4; ++q) acc[q] += sv[q] * w2;
  };

  // chunk 0/1 indices from preloaded srclist (j < 32)
  int s0, s1; bool v0, v1;
  { const int j = es;      v0 = j < deg; const int t0 = __shfl(myidx, half*32 + j); s0 = v0 ? t0 : 0; }
  { const int j = 16 + es; v1 = j < deg; const int t1 = __shfl(myidx, half*32 + j); s1 = v1 ? t1 : 0; }

  uint4 A0, A1;
  if (nbw > 0) A0 = sp[(hN + s0) * 2 + dh];
  if (nbw > 1) A1 = sp[(hN + s1) * 2 + dh];
  if (nbw > 0) COMP(v0, A0);
  if (nbw > 1) COMP(v1, A1);
  if (nbw > 2){
    for (int c = 2; c < nbw; ++c){      // deg > 32: rare (Poisson(16))
      const int j = c * 16 + es;
      const bool v = j < deg;
      const int s = v ? (int)srclist[lo + j] : 0;
      const uint4 A = sp[(hN + s) * 2 + dh];
      COMP(v, A);
    }
  }

  // denom: butterfly over the 16 es-lanes (dh copies identical)
  #pragma unroll
  for (int m = 2; m <= 16; m <<= 1) denom += __shfl_xor(denom, m);

  // acc reduce-scatter over es: 8 floats -> each lane owns 1 dim (8 shfls)
  float af[8];
  af[0]=acc[0].x; af[1]=acc[0].y; af[2]=acc[1].x; af[3]=acc[1].y;
  af[4]=acc[2].x; af[5]=acc[2].y; af[6]=acc[3].x; af[7]=acc[3].y;
  float b4[4];
  #pragma unroll
  for (int k = 0; k < 4; ++k){
    const float give = (lane & 2) ? af[k] : af[4 + k];
    const float got = __shfl_xor(give, 2);
    b4[k] = ((lane & 2) ? af[4 + k] : af[k]) + got;
  }
  float c2[2];
  #pragma unroll
  for (int k = 0; k < 2; ++k){
    const float give = (lane & 4) ? b4[k] : b4[2 + k];
    const float got = __shfl_xor(give, 4);
    c2[k] = ((lane & 4) ? b4[2 + k] : b4[k]) + got;
  }
  float d1;
  {
    const float give = (lane & 8) ? c2[0] : c2[1];
    const float got = __shfl_xor(give, 8);
    d1 = ((lane & 8) ? c2[1] : c2[0]) + got;
  }
  d1 += __shfl_xor(d1, 16);   // merge the two es-bit3 copies

  const float inv = 1.f / (denom + 1e-16f);
  // dim owned by this lane (within the head's 16)
  const int dim = dh * 8 + ((lane & 2) ? 4 : 0) + ((lane & 4) ? 2 : 0) + ((lane & 8) ? 1 : 0);
  const int col = h * 16 + dim;
  const float xr = x[(size_t)i * 128 + col];
  const float bv = bias[col];
  const float al = palpha[0];
  float tv = fmaf(d1, inv, xr) + bv;
  const float o = (tv > 0.f) ? tv : al * tv;
  if ((lane & 16) == 0) outp[(size_t)i * 128 + col] = o;  // one copy stores (16 lanes = 64B)

  // gate-logit partial for this head: sum o*ww over the 16 dims
  float z = (lane & 16) ? 0.f : o * ww[col];
  z += __shfl_xor(z, 1); z += __shfl_xor(z, 2); z += __shfl_xor(z, 4);
  z += __shfl_xor(z, 8); z += __shfl_xor(z, 16);
  if (l32 == 0) atomicAdd(&wsum[i], z);
}

// ---------------- readout: one block per graph -------------------------------
// wsum holds the pre-sigmoid gate logit (sum of 8 per-head partials);
// sigmoid (+ bw) applied here.
__global__ __launch_bounds__(256) void readout_kernel(
    const float* __restrict__ outp, const float* __restrict__ wsumv,
    const int* __restrict__ batchv, const float* __restrict__ bw,
    const float* __restrict__ wscore, const float* __restrict__ bscore,
    float* __restrict__ ro)
{
  __shared__ int range_s[2];
  __shared__ float wsum_s[128];
  __shared__ float max_s[128];
  __shared__ float wtot_s[2];
  __shared__ float part_s[256];
  const int g = blockIdx.x, t = threadIdx.x;
  const int col = t & 127, grp = t >> 7;
  const float bw0 = bw[0];
  if (t < 2){
    const int target = g + t;
    int lo = 0, hi = NODES;
    while (lo < hi){ const int m = (lo + hi) >> 1; if (batchv[m] < target) lo = m + 1; else hi = m; }
    range_s[t] = lo;
  }
  __syncthreads();
  const int lo = range_s[0], hi = range_s[1];
  float acc = 0.f, vmax = -INFINITY, wacc = 0.f;
  for (int n = lo + grp; n < hi; n += 2){
    const float w = 1.f / (1.f + __expf(-(wsumv[n] + bw0)));
    const float v = outp[n * 128 + col];
    acc = fmaf(w, v, acc);
    vmax = fmaxf(vmax, v);
    if (col == 0) wacc += w;
  }
  part_s[t] = acc;
  if (col == 0) wtot_s[grp] = wacc;
  __syncthreads();
  if (grp == 0) wsum_s[col] = acc + part_s[col + 128];
  __syncthreads();
  part_s[t] = vmax;
  __syncthreads();
  if (grp == 0) max_s[col] = fmaxf(vmax, part_s[col + 128]);
  const float wtot = wtot_s[0] + wtot_s[1];
  __syncthreads();
  float dot = 0.f;
  const float* wr = wscore + col * 128 + grp * 64;
  const float* xs = wsum_s + grp * 64;
  #pragma unroll
  for (int k = 0; k < 64; ++k) dot = fmaf(wr[k], xs[k], dot);
  part_s[t] = dot;
  __syncthreads();
  if (grp == 0){
    const float s = dot + part_s[col + 128] + wtot * bscore[col];
    ro[g * 256 + col] = s;
    ro[g * 256 + 128 + col] = max_s[col];
  }
}

extern "C" void kernel_launch(void* const* d_in, const int* in_sizes, int n_in,
                              void* d_out, int out_size, void* d_ws, size_t ws_size,
                              hipStream_t stream)
{
  const float* x      = (const float*)d_in[0];
  const int*   ei     = (const int*)d_in[1];
  const int*   batchv = (const int*)d_in[2];
  const float* Wsrc   = (const float*)d_in[3];
  const float* Wdst   = (const float*)d_in[4];
  const float* attn   = (const float*)d_in[5];
  const float* bias   = (const float*)d_in[6];
  const float* palpha = (const float*)d_in[7];
  const float* ww     = (const float*)d_in[8];
  const float* bw     = (const float*)d_in[9];
  const float* wsc    = (const float*)d_in[10];
  const float* bsc    = (const float*)d_in[11];

  char* ws = (char*)d_ws;
  u16*  srcp      = (u16*) (ws + 0);          // 12,800,000 B (bf16, [H][N][16])
  u16*  dstp      = (u16*) (ws + 12800000);   // 12,800,000 B (bf16, [H][N][16])
  u16*  srclist   = (u16*) (ws + 25600000);   //  1,600,000 B (u16 src ids)
  int*  row_start = (int*) (ws + 28800000);   //    200,004 B
  int*  bcount    = (int*) (ws + 29000192);   //    153,664 B (ABLK*NB, [chunk][bucket])
  int*  bstart    = (int*) (ws + 29153856);   //        788 B
  float* wsum     = (float*)(ws + 29154688);  //    200,000 B (pre-sigmoid gate logit)

  float* outp = (float*)d_out;                // [N,128] fp32
  float* ro = outp + NODES * FEAT;            // [G,256] fp32
  u32* ebuf = (u32*)d_out;                    // scratch alias: dead until aggregate

  proj_hist_kernel<<<PROJ_BLOCKS + ABLK, 256, 0, stream>>>(
      x, Wsrc, Wdst, srcp, dstp, ei, bcount);
  bucket_scatter_kernel<<<ABLK, 256, 0, stream>>>(ei, bcount, bstart, ebuf, wsum);
  bucket_csr_kernel<<<NB, 256, 0, stream>>>(ebuf, bstart, row_start, srclist);
  aggregate_kernel<<<(NODES / 8) * 8, 256, 0, stream>>>(srcp, dstp, row_start, srclist,
                                                        x, attn, bias, palpha, ww,
                                                        outp, wsum);
  readout_kernel<<<GRAPHS, 256, 0, stream>>>(outp, wsum, batchv, bw, wsc, bsc, ro);
}

// Round 5
// 223.895 us; speedup vs baseline: 1.1418x; 1.1418x over previous
//
#include <hip/hip_runtime.h>

#define NODES 50000
#define FEAT 128
#define EDGES 800000
#define GRAPHS 512
#define NB 196      // dst buckets (dst >> 8), 196*256 = 50176 >= NODES
#define CHUNK 4096
#define ABLK 196    // ceil(EDGES/CHUNK)
#define BCAP 8192   // max edges per bucket (mean 4082, max ~4400)
#define PROJ_BLOCKS 782

typedef unsigned int u32;
typedef unsigned short u16;
typedef __attribute__((ext_vector_type(8))) short short8;   // 8 bf16 = 4 VGPRs
typedef __attribute__((ext_vector_type(4))) float v4f;      // MFMA accumulator
typedef __attribute__((ext_vector_type(4))) u32 u32x4;
typedef __attribute__((ext_vector_type(2))) float f2;       // packed-fp32 pair

static __device__ __forceinline__ float bflo(u32 u){ return __uint_as_float(u << 16); }
static __device__ __forceinline__ float bfhi(u32 u){ return __uint_as_float(u & 0xffff0000u); }
static __device__ __forceinline__ u16 f2bf(float f){
  u32 u = __float_as_uint(f);
  u32 r = u + 0x7fffu + ((u >> 16) & 1u);
  return (u16)(r >> 16);
}
static __device__ __forceinline__ u32 packbf(float a, float b){
  return (u32)f2bf(a) | ((u32)f2bf(b) << 16);
}
static __device__ __forceinline__ f2 unpk(u32 u){ f2 r; r.x = bflo(u); r.y = bfhi(u); return r; }
static __device__ __forceinline__ f2 vmax2(f2 a, f2 b){ f2 r; r.x = fmaxf(a.x,b.x); r.y = fmaxf(a.y,b.y); return r; }

// ---------------- fused: MFMA projection (blocks 0..781) + bucket hist -------
// srcp/dstp are HEAD-MAJOR: [H][NODES][16] bf16, so the aggregate kernel's
// per-head gather footprint is 1.6 MB (fits a 4 MiB per-XCD L2).
#define LROW 68
__global__ __launch_bounds__(256) void proj_hist_kernel(
    const float* __restrict__ x, const float* __restrict__ Wsrc,
    const float* __restrict__ Wdst, u16* __restrict__ srcp, u16* __restrict__ dstp,
    const int* __restrict__ ei, int* __restrict__ bcount)
{
  __shared__ u32 x_lds[64 * LROW];
  __shared__ int cnt[NB];
  const int t = threadIdx.x;

  if (blockIdx.x >= PROJ_BLOCKS){
    // ---- histogram role ----
    const int b = blockIdx.x - PROJ_BLOCKS;
    for (int k = t; k < NB; k += 256) cnt[k] = 0;
    __syncthreads();
    const int e0 = b * CHUNK;
    const int e1 = (e0 + CHUNK < EDGES) ? e0 + CHUNK : EDGES;
    for (int e = e0 + t; e < e1; e += 256)
      atomicAdd(&cnt[ei[EDGES + e] >> 8], 1);
    __syncthreads();
    // transposed layout: bcount[chunk][bucket] -> coalesced
    for (int k = t; k < NB; k += 256) bcount[b * NB + k] = cnt[k];
    return;
  }

  // ---- projection role ----
  const int node0 = blockIdx.x * 64;
  const int rows_valid = NODES - node0 < 64 ? NODES - node0 : 64;
  const float4* xp = (const float4*)(x + (size_t)node0 * 128);
  for (int idx = t; idx < rows_valid * 32; idx += 256){
    const float4 v = xp[idx];
    const int row = idx >> 5, cq = idx & 31;
    x_lds[row * LROW + cq * 2]     = packbf(v.x, v.y);
    x_lds[row * LROW + cq * 2 + 1] = packbf(v.z, v.w);
  }

  const int wave = t >> 6, lane = t & 63;
  const int r16 = lane & 15;
  const int quad = lane >> 4;
  const int ko = quad * 4;
  const int n0 = wave * 32;

  short8 bs[2][4], bd[2][4];
  #pragma unroll
  for (int nt = 0; nt < 2; ++nt){
    const int col = n0 + nt * 16 + r16;
    #pragma unroll
    for (int k = 0; k < 4; ++k){
      const float4* wp = (const float4*)(Wsrc + col * 128 + quad * 8 + k * 32);
      float4 w0 = wp[0], w1 = wp[1];
      u32x4 pk; pk.x = packbf(w0.x,w0.y); pk.y = packbf(w0.z,w0.w);
      pk.z = packbf(w1.x,w1.y); pk.w = packbf(w1.z,w1.w);
      bs[nt][k] = __builtin_bit_cast(short8, pk);
      const float4* vp = (const float4*)(Wdst + col * 128 + quad * 8 + k * 32);
      float4 v0 = vp[0], v1 = vp[1];
      u32x4 qk; qk.x = packbf(v0.x,v0.y); qk.y = packbf(v0.z,v0.w);
      qk.z = packbf(v1.x,v1.y); qk.w = packbf(v1.z,v1.w);
      bd[nt][k] = __builtin_bit_cast(short8, qk);
    }
  }
  __syncthreads();

  #pragma unroll
  for (int mt = 0; mt < 4; ++mt){
    const int node_base = node0 + mt * 16;
    if (node_base >= NODES) break;
    short8 afr[4];
    #pragma unroll
    for (int k = 0; k < 4; ++k)
      afr[k] = *(const short8*)&x_lds[(mt * 16 + r16) * LROW + ko + k * 16];
    v4f s0 = {0.f,0.f,0.f,0.f}, s1 = s0, d0 = s0, d1 = s0;
    #pragma unroll
    for (int k = 0; k < 4; ++k){
      s0 = __builtin_amdgcn_mfma_f32_16x16x32_bf16(afr[k], bs[0][k], s0, 0, 0, 0);
      s1 = __builtin_amdgcn_mfma_f32_16x16x32_bf16(afr[k], bs[1][k], s1, 0, 0, 0);
      d0 = __builtin_amdgcn_mfma_f32_16x16x32_bf16(afr[k], bd[0][k], d0, 0, 0, 0);
      d1 = __builtin_amdgcn_mfma_f32_16x16x32_bf16(afr[k], bd[1][k], d1, 0, 0, 0);
    }
    // C/D layout: col = lane&15, row = quad*4 + reg  [verified m89/m91]
    const int node = node_base + quad * 4;
    u16* so0 = srcp + ((size_t)(wave*2)   * NODES + node) * 16 + r16;
    u16* so1 = srcp + ((size_t)(wave*2+1) * NODES + node) * 16 + r16;
    u16* dd0 = dstp + ((size_t)(wave*2)   * NODES + node) * 16 + r16;
    u16* dd1 = dstp + ((size_t)(wave*2+1) * NODES + node) * 16 + r16;
    #pragma unroll
    for (int r = 0; r < 4; ++r){
      so0[r * 16] = f2bf(s0[r]);
      so1[r * 16] = f2bf(s1[r]);
      dd0[r * 16] = f2bf(d0[r]);
      dd1[r * 16] = f2bf(d1[r]);
    }
  }
}

// ---------------- scatter with inline scan (R2-benched version) --------------
// Reverted to the exact version that ran in the R2 bench, to bisect the
// container failure: only aggregate_kernel differs from the benched build.
// Also zeroes the per-node gate-logit accumulator (wsum).
__global__ __launch_bounds__(256) void bucket_scatter_kernel(
    const int* __restrict__ ei, const int* __restrict__ bcount,
    int* __restrict__ bstart_g, u32* __restrict__ ebuf, float* __restrict__ wsum)
{
  __shared__ int tot[256];
  __shared__ int bstart_s[NB + 1];
  __shared__ int obase_s[NB];
  __shared__ int cur[NB];
  const int b = blockIdx.x, t = threadIdx.x;
  const int nid = b * 256 + t;
  if (nid < NODES) wsum[nid] = 0.f;
  int total = 0, obase = 0;
  if (t < NB){
    int run = 0;
    for (int q = 0; q < ABLK; ++q){
      if (q == b) obase = run;
      run += bcount[q * NB + t];   // coalesced: consecutive t -> consecutive addr
    }
    total = run;
  }
  tot[t] = total;
  __syncthreads();
  const int v = total;
  for (int off = 1; off < 256; off <<= 1){
    const int add = (t >= off) ? tot[t - off] : 0;
    __syncthreads();
    tot[t] += add;
    __syncthreads();
  }
  if (t < NB){
    bstart_s[t] = tot[t] - v;
    obase_s[t] = obase;
    cur[t] = 0;
  }
  if (t == NB - 1) bstart_s[NB] = tot[t];
  __syncthreads();
  if (b == 0 && t <= NB) bstart_g[t] = bstart_s[t];

  const int e0 = b * CHUNK;
  const int e1 = (e0 + CHUNK < EDGES) ? e0 + CHUNK : EDGES;
  for (int e = e0 + t; e < e1; e += 256){
    const int d = ei[EDGES + e];
    const int s = ei[e];
    const int k = d >> 8;
    const int r = atomicAdd(&cur[k], 1);
    ebuf[bstart_s[k] + obase_s[k] + r] = (u32)s | ((u32)(d & 255) << 16);
  }
}

// ---------------- B4: one block per bucket: local CSR in LDS -----------------
__global__ __launch_bounds__(256) void bucket_csr_kernel(
    const u32* __restrict__ ebuf, const int* __restrict__ bstart,
    int* __restrict__ row_start, u16* __restrict__ srclist)
{
  __shared__ int cnt[256], excl[256], cur[256];
  __shared__ u32 loc[BCAP];
  const int k = blockIdx.x, t = threadIdx.x;
  const int base = bstart[k];
  int ne = bstart[k + 1] - base;
  if (ne > BCAP) ne = BCAP;
  cnt[t] = 0;
  __syncthreads();
  for (int j = t; j < ne; j += 256)
    atomicAdd(&cnt[(ebuf[base + j] >> 16) & 255], 1);
  __syncthreads();
  const int v = cnt[t];
  for (int off = 1; off < 256; off <<= 1){
    const int add = (t >= off) ? cnt[t - off] : 0;
    __syncthreads();
    cnt[t] += add;
    __syncthreads();
  }
  excl[t] = cnt[t] - v;
  cur[t] = cnt[t] - v;
  __syncthreads();
  const int node = k * 256 + t;
  if (node <= NODES) row_start[node] = base + excl[t];
  for (int j = t; j < ne; j += 256){
    const u32 e = ebuf[base + j];
    const int p = atomicAdd(&cur[(e >> 16) & 255], 1);
    loc[p] = e & 0xFFFFu;
  }
  __syncthreads();
  for (int j = t; j < ne; j += 256)
    srclist[base + j] = (u16)loc[j];
}

// ---------------- fused attention aggregation (head-per-block, full-lane) ---
// h = blockIdx&7 pins each head's 1.6 MB srcp slice to one XCD's L2 (the part
// of R1 that worked: FETCH 99->45 MB). VALU efficiency restored to R0 level:
// each lane owns a FULL edge-head (16 dims, 2x uint4 gather), logit completes
// in-lane. Wave = 8 nodes x 8 edge-slots; epilogue reduce-scatters 16 dims
// over the 8 es-lanes so lane es owns dims {2es,2es+1} (float2 coalesced io).
__global__ __launch_bounds__(256, 4) void aggregate_kernel(
    const u16* __restrict__ srcp, const u16* __restrict__ dstp,
    const int* __restrict__ row_start, const u16* __restrict__ srclist,
    const float* __restrict__ x, const float* __restrict__ attn,
    const float* __restrict__ bias, const float* __restrict__ palpha,
    const float* __restrict__ ww, float* __restrict__ outp,
    float* __restrict__ wsum)
{
  const int h   = blockIdx.x & 7;     // head, pinned to XCD (round-robin)
  const int grp = blockIdx.x >> 3;    // 32 nodes per block (4 waves x 8)
  const int wv = threadIdx.x >> 6;
  const int lane = threadIdx.x & 63;
  const int nd = lane >> 3;           // node within wave (0..7)
  const int es = lane & 7;            // edge slot (0..7)
  const int i = grp * 32 + wv * 8 + nd;
  const bool vn = i < NODES;
  const int ic = vn ? i : NODES - 1;
  const size_t hN = (size_t)h * NODES;
  const uint4* sp = (const uint4*)srcp;

  // dst fragment + attention vector: full 16 dims per lane
  f2 d2[8], a2[8];
  {
    const uint4 dA = ((const uint4*)dstp)[(hN + ic) * 2];
    const uint4 dB = ((const uint4*)dstp)[(hN + ic) * 2 + 1];
    d2[0]=unpk(dA.x); d2[1]=unpk(dA.y); d2[2]=unpk(dA.z); d2[3]=unpk(dA.w);
    d2[4]=unpk(dB.x); d2[5]=unpk(dB.y); d2[6]=unpk(dB.z); d2[7]=unpk(dB.w);
    const float4* ap = (const float4*)(attn + h * 16);
    const float4 a0 = ap[0], a1 = ap[1], a2v = ap[2], a3v = ap[3];
    a2[0].x=a0.x;  a2[0].y=a0.y;  a2[1].x=a0.z;  a2[1].y=a0.w;
    a2[2].x=a1.x;  a2[2].y=a1.y;  a2[3].x=a1.z;  a2[3].y=a1.w;
    a2[4].x=a2v.x; a2[4].y=a2v.y; a2[5].x=a2v.z; a2[5].y=a2v.w;
    a2[6].x=a3v.x; a2[6].y=a3v.y; a2[7].x=a3v.z; a2[7].y=a3v.w;
  }
  const int lo = vn ? row_start[i] : 0;
  const int hi = vn ? row_start[i + 1] : 0;
  const int deg = hi - lo;
  const int nb = (deg + 7) >> 3;
  int nbw = nb;
  { int o = __shfl_xor(nbw, 8);  if (o > nbw) nbw = o; }
  { int o = __shfl_xor(nbw, 16); if (o > nbw) nbw = o; }
  { int o = __shfl_xor(nbw, 32); if (o > nbw) nbw = o; }

  f2 acc[8];
  #pragma unroll
  for (int q = 0; q < 8; ++q){ acc[q].x = 0.f; acc[q].y = 0.f; }
  float denom = 0.f;

  auto FETCH = [&](int c, uint4& A, uint4& B, bool& v){
    const int j = c * 8 + es;
    v = j < deg;
    const int s = v ? (int)srclist[lo + j] : 0;
    const uint4* rp = sp + (hN + s) * 2;
    A = rp[0]; B = rp[1];
  };
  auto COMP = [&](bool v, const uint4& A, const uint4& B){
    f2 sv[8];
    sv[0]=unpk(A.x); sv[1]=unpk(A.y); sv[2]=unpk(A.z); sv[3]=unpk(A.w);
    sv[4]=unpk(B.x); sv[5]=unpk(B.y); sv[6]=unpk(B.z); sv[7]=unpk(B.w);
    f2 p; p.x = 0.f; p.y = 0.f;
    #pragma unroll
    for (int q = 0; q < 8; ++q){
      f2 e = sv[q] + d2[q];
      e = vmax2(e, e * 0.2f);
      p += e * a2[q];
    }
    const float w = v ? __expf(p.x + p.y) : 0.f;
    denom += w;
    f2 w2; w2.x = w; w2.y = w;
    #pragma unroll
    for (int q = 0; q < 8; ++q) acc[q] += sv[q] * w2;
  };

  uint4 A0, B0, A1, B1; bool v0 = false, v1 = false;
  if (nbw > 0) FETCH(0, A0, B0, v0);
  if (nbw > 1) FETCH(1, A1, B1, v1);
  if (nbw > 0){ COMP(v0, A0, B0); if (nbw > 2) FETCH(2, A0, B0, v0); }
  if (nbw > 1){ COMP(v1, A1, B1); if (nbw > 3) FETCH(3, A1, B1, v1); }
  if (nbw > 2) COMP(v0, A0, B0);
  if (nbw > 3) COMP(v1, A1, B1);
  if (nbw > 4){
    for (int c = 4; c < nbw; ++c){   // deg > 32: rare
      uint4 TA, TB; bool tv;
      FETCH(c, TA, TB, tv);
      COMP(tv, TA, TB);
    }
  }

  // denom over the 8 es-lanes
  denom += __shfl_xor(denom, 1);
  denom += __shfl_xor(denom, 2);
  denom += __shfl_xor(denom, 4);
  const float inv = 1.f / (denom + 1e-16f);

  // reduce-scatter acc (16 dims) over 8 es-lanes -> lane es owns {2es,2es+1}
  float v8[8];
  #pragma unroll
  for (int q = 0; q < 4; ++q){
    const float gx = (es & 4) ? acc[q].x : acc[4 + q].x;
    const float gy = (es & 4) ? acc[q].y : acc[4 + q].y;
    const float rx = __shfl_xor(gx, 4);
    const float ry = __shfl_xor(gy, 4);
    v8[2*q]   = ((es & 4) ? acc[4 + q].x : acc[q].x) + rx;
    v8[2*q+1] = ((es & 4) ? acc[4 + q].y : acc[q].y) + ry;
  }
  float v4a[4];
  #pragma unroll
  for (int q = 0; q < 2; ++q){
    const float gx = (es & 2) ? v8[2*q]   : v8[4 + 2*q];
    const float gy = (es & 2) ? v8[2*q+1] : v8[4 + 2*q+1];
    const float rx = __shfl_xor(gx, 2);
    const float ry = __shfl_xor(gy, 2);
    v4a[2*q]   = ((es & 2) ? v8[4 + 2*q]   : v8[2*q]) + rx;
    v4a[2*q+1] = ((es & 2) ? v8[4 + 2*q+1] : v8[2*q+1]) + ry;
  }
  float r0, r1;
  {
    const float g0 = (es & 1) ? v4a[0] : v4a[2];
    const float g1 = (es & 1) ? v4a[1] : v4a[3];
    const float q0 = __shfl_xor(g0, 1);
    const float q1 = __shfl_xor(g1, 1);
    r0 = ((es & 1) ? v4a[2] : v4a[0]) + q0;
    r1 = ((es & 1) ? v4a[3] : v4a[1]) + q1;
  }

  const int col = h * 16 + es * 2;
  const f2 xr = *(const f2*)(x + (size_t)ic * 128 + col);
  const f2 bv = *(const f2*)(bias + col);
  const float al = palpha[0];
  const float t0 = fmaf(r0, inv, xr.x) + bv.x;
  const float t1 = fmaf(r1, inv, xr.y) + bv.y;
  const float o0 = (t0 > 0.f) ? t0 : al * t0;
  const float o1 = (t1 > 0.f) ? t1 : al * t1;
  if (vn){
    f2 ov; ov.x = o0; ov.y = o1;
    *(f2*)(outp + (size_t)i * 128 + col) = ov;
  }
  const f2 gv = *(const f2*)(ww + col);
  float z = o0 * gv.x + o1 * gv.y;
  z += __shfl_xor(z, 1);
  z += __shfl_xor(z, 2);
  z += __shfl_xor(z, 4);
  if (vn && es == 0) atomicAdd(&wsum[i], z);
}

// ---------------- readout: one block per graph -------------------------------
// wsum holds the pre-sigmoid gate logit (sum of 8 per-head partials);
// sigmoid (+ bw) applied here.
__global__ __launch_bounds__(256) void readout_kernel(
    const float* __restrict__ outp, const float* __restrict__ wsumv,
    const int* __restrict__ batchv, const float* __restrict__ bw,
    const float* __restrict__ wscore, const float* __restrict__ bscore,
    float* __restrict__ ro)
{
  __shared__ int range_s[2];
  __shared__ float wsum_s[128];
  __shared__ float max_s[128];
  __shared__ float wtot_s[2];
  __shared__ float part_s[256];
  const int g = blockIdx.x, t = threadIdx.x;
  const int col = t & 127, grp = t >> 7;
  const float bw0 = bw[0];
  if (t < 2){
    const int target = g + t;
    int lo = 0, hi = NODES;
    while (lo < hi){ const int m = (lo + hi) >> 1; if (batchv[m] < target) lo = m + 1; else hi = m; }
    range_s[t] = lo;
  }
  __syncthreads();
  const int lo = range_s[0], hi = range_s[1];
  float acc = 0.f, vmax = -INFINITY, wacc = 0.f;
  for (int n = lo + grp; n < hi; n += 2){
    const float w = 1.f / (1.f + __expf(-(wsumv[n] + bw0)));
    const float v = outp[n * 128 + col];
    acc = fmaf(w, v, acc);
    vmax = fmaxf(vmax, v);
    if (col == 0) wacc += w;
  }
  part_s[t] = acc;
  if (col == 0) wtot_s[grp] = wacc;
  __syncthreads();
  if (grp == 0) wsum_s[col] = acc + part_s[col + 128];
  __syncthreads();
  part_s[t] = vmax;
  __syncthreads();
  if (grp == 0) max_s[col] = fmaxf(vmax, part_s[col + 128]);
  const float wtot = wtot_s[0] + wtot_s[1];
  __syncthreads();
  float dot = 0.f;
  const float* wr = wscore + col * 128 + grp * 64;
  const float* xs = wsum_s + grp * 64;
  #pragma unroll
  for (int k = 0; k < 64; ++k) dot = fmaf(wr[k], xs[k], dot);
  part_s[t] = dot;
  __syncthreads();
  if (grp == 0){
    const float s = dot + part_s[col + 128] + wtot * bscore[col];
    ro[g * 256 + col] = s;
    ro[g * 256 + 128 + col] = max_s[col];
  }
}

extern "C" void kernel_launch(void* const* d_in, const int* in_sizes, int n_in,
                              void* d_out, int out_size, void* d_ws, size_t ws_size,
                              hipStream_t stream)
{
  const float* x      = (const float*)d_in[0];
  const int*   ei     = (const int*)d_in[1];
  const int*   batchv = (const int*)d_in[2];
  const float* Wsrc   = (const float*)d_in[3];
  const float* Wdst   = (const float*)d_in[4];
  const float* attn   = (const float*)d_in[5];
  const float* bias   = (const float*)d_in[6];
  const float* palpha = (const float*)d_in[7];
  const float* ww     = (const float*)d_in[8];
  const float* bw     = (const float*)d_in[9];
  const float* wsc    = (const float*)d_in[10];
  const float* bsc    = (const float*)d_in[11];

  char* ws = (char*)d_ws;
  u16*  srcp      = (u16*) (ws + 0);          // 12,800,000 B (bf16, [H][N][16])
  u16*  dstp      = (u16*) (ws + 12800000);   // 12,800,000 B (bf16, [H][N][16])
  u16*  srclist   = (u16*) (ws + 25600000);   //  1,600,000 B (u16 src ids)
  int*  row_start = (int*) (ws + 28800000);   //    200,004 B
  int*  bcount    = (int*) (ws + 29000192);   //    153,664 B (ABLK*NB, [chunk][bucket])
  int*  bstart    = (int*) (ws + 29153856);   //        788 B
  float* wsum     = (float*)(ws + 29154688);  //    200,000 B (pre-sigmoid gate logit)

  float* outp = (float*)d_out;                // [N,128] fp32
  float* ro = outp + NODES * FEAT;            // [G,256] fp32
  u32* ebuf = (u32*)d_out;                    // scratch alias: dead until aggregate

  proj_hist_kernel<<<PROJ_BLOCKS + ABLK, 256, 0, stream>>>(
      x, Wsrc, Wdst, srcp, dstp, ei, bcount);
  bucket_scatter_kernel<<<ABLK, 256, 0, stream>>>(ei, bcount, bstart, ebuf, wsum);
  bucket_csr_kernel<<<NB, 256, 0, stream>>>(ebuf, bstart, row_start, srclist);
  const int ngrp = (NODES + 31) / 32;         // 1563 node groups x 8 heads
  aggregate_kernel<<<ngrp * 8, 256, 0, stream>>>(srcp, dstp, row_start, srclist,
                                                 x, attn, bias, palpha, ww,
                                                 outp, wsum);
  readout_kernel<<<GRAPHS, 256, 0, stream>>>(outp, wsum, batchv, bw, wsc, bsc, ro);
}